// Round 9
// baseline (30.361 us; speedup 1.0000x reference)
//
#include <hip/hip_runtime.h>
#include <math.h>

#define B_ 4096
#define D_ 256
#define C_ 64
#define BD (B_*D_)

__device__ __forceinline__ float wave_reduce_sum(float v) {
    #pragma unroll
    for (int off = 1; off < 64; off <<= 1) v += __shfl_xor(v, off);
    return v;
}

// full sum across each aligned 16-lane group, result in all 16 lanes (VALU-only DPP)
__device__ __forceinline__ float dpp_sum16(float v) {
    int t;
    t = __builtin_amdgcn_update_dpp(0, __float_as_int(v), 0x121, 0xF, 0xF, true); v += __int_as_float(t); // ror:1
    t = __builtin_amdgcn_update_dpp(0, __float_as_int(v), 0x122, 0xF, 0xF, true); v += __int_as_float(t); // ror:2
    t = __builtin_amdgcn_update_dpp(0, __float_as_int(v), 0x124, 0xF, 0xF, true); v += __int_as_float(t); // ror:4
    t = __builtin_amdgcn_update_dpp(0, __float_as_int(v), 0x128, 0xF, 0xF, true); v += __int_as_float(t); // ror:8
    return v;
}

// ---- fused: x-copy stripe + Sum(x^2) partial, slice-local bucket scan,
//      W-L1 partial (sl==0), grouped matvec.
//      grid = 64 conds x 4 ot x 8 sl = 2048 blocks -> 8 blocks/CU ----
__global__ __launch_bounds__(256) void k_main(const float* __restrict__ W,
                                              const float* __restrict__ b,
                                              const float* __restrict__ x,
                                              const int* __restrict__ c,
                                              float* __restrict__ out,
                                              float* __restrict__ l1p,
                                              float* __restrict__ xsqp,
                                              int* __restrict__ cnt8) {
    int hw = blockIdx.x;
    int bid = (hw & 7) * 256 + (hw >> 3);   // XCD swizzle: 256 consecutive logical blocks per XCD
    int cond = bid >> 5;                    // 32 blocks per cond, all on one XCD
    int ot = (bid >> 3) & 3;
    int sl = bid & 7;
    int tid = threadIdx.x;
    int rg = tid >> 4, kseg = tid & 15;
    int swz = kseg >> 1;
    int row0 = ot * 64 + rg * 4;

    // --- issue independent loads early: W strip, x-copy stripe, c slice-scan ---
    float4 Wreg[4][4];
    #pragma unroll
    for (int rr = 0; rr < 4; ++rr) {
        const float4* wp = (const float4*)(W + (size_t)cond * (D_ * D_) + (size_t)(row0 + rr) * D_ + kseg * 16);
        #pragma unroll
        for (int j = 0; j < 4; ++j) Wreg[rr][j] = wp[j];
    }
    int xi = bid * 128 + tid;               // 128 float4 per block (tid<128 active)
    float4 xv = make_float4(0.f, 0.f, 0.f, 0.f);
    if (tid < 128) xv = ((const float4*)x)[xi];
    // slice sl owns samples i == sl (mod 8): candidate j -> sample 8j+sl,
    // c[8j+sl] = int4[2j + (sl>>2)] component (sl&3)
    int cbase = sl >> 2, ccomp = sl & 3;
    int4 cq0 = ((const int4*)c)[2 * tid + cbase];
    int4 cq1 = ((const int4*)c)[2 * (tid + 256) + cbase];

    #pragma unroll
    for (int rr = 0; rr < 4; ++rr)
        #pragma unroll
        for (int j = 0; j < 4; ++j)
            asm volatile("" : "+v"(Wreg[rr][j].x), "+v"(Wreg[rr][j].y), "+v"(Wreg[rr][j].z), "+v"(Wreg[rr][j].w));

    __shared__ float part_x[4];
    __shared__ float part_w[4];
    __shared__ int slist[512];
    __shared__ int nlist;
    if (tid == 0) nlist = 0;

    // x copy to out tail + sumsq partial
    if (tid < 128) {
        float2* dst = (float2*)(out + BD + 2);
        dst[2 * xi]     = make_float2(xv.x, xv.y);
        dst[2 * xi + 1] = make_float2(xv.z, xv.w);
    }
    float s = xv.x * xv.x + xv.y * xv.y + xv.z * xv.z + xv.w * xv.w;
    s = wave_reduce_sum(s);
    int wid = tid >> 6, lane = tid & 63;
    if (lane == 0) part_x[wid] = s;

    // |W| L1 partial (only sl==0 blocks: W counted exactly once overall)
    if (sl == 0) {
        float a = 0.f;
        #pragma unroll
        for (int rr = 0; rr < 4; ++rr)
            #pragma unroll
            for (int j = 0; j < 4; ++j)
                a += fabsf(Wreg[rr][j].x) + fabsf(Wreg[rr][j].y) + fabsf(Wreg[rr][j].z) + fabsf(Wreg[rr][j].w);
        a = wave_reduce_sum(a);
        if (lane == 0) part_w[wid] = a;
    }
    __syncthreads();
    if (tid == 0) {
        xsqp[bid] = (part_x[0] + part_x[1]) + (part_x[2] + part_x[3]);
        if (sl == 0) l1p[cond * 4 + ot] = (part_w[0] + part_w[1]) + (part_w[2] + part_w[3]);
    }

    // slice-local bucket scan (512 candidates, 2 per thread)
    {
        int c0 = (ccomp == 0) ? cq0.x : (ccomp == 1) ? cq0.y : (ccomp == 2) ? cq0.z : cq0.w;
        int c1 = (ccomp == 0) ? cq1.x : (ccomp == 1) ? cq1.y : (ccomp == 2) ? cq1.z : cq1.w;
        if (c0 == cond) { int p = atomicAdd(&nlist, 1); slist[p] = 8 * tid + sl; }
        if (c1 == cond) { int p = atomicAdd(&nlist, 1); slist[p] = 8 * (tid + 256) + sl; }
    }
    __syncthreads();
    int n = nlist;
    if (ot == 0 && tid == 0) cnt8[cond * 8 + sl] = n;

    float4 bias = ((const float4*)(b + cond * D_ + ot * 64))[rg];

    __shared__ float4 xs[16 * 64];          // 16-sample tile (avg n ~ 8)
    for (int s0 = 0; s0 < n; s0 += 16) {
        int ns = min(16, n - s0);
        __syncthreads();
        for (int u = tid; u < ns * 64; u += 256) {
            int si = u >> 6, v = u & 63;
            int sg = slist[s0 + si];
            xs[si * 64 + (v & 0x3C) + (((v & 3) + (v >> 3)) & 3)] = ((const float4*)x)[(size_t)sg * 64 + v];
        }
        __syncthreads();
        for (int si = 0; si < ns; ++si) {
            const float4* xp = &xs[si * 64 + kseg * 4];
            float4 a0 = make_float4(0.f, 0.f, 0.f, 0.f);
            float4 a1 = a0, a2 = a0, a3 = a0;
            #pragma unroll
            for (int jl = 0; jl < 4; ++jl) {
                float4 q = xp[(jl + swz) & 3];
                a0.x += Wreg[0][jl].x * q.x; a0.y += Wreg[0][jl].y * q.y;
                a0.z += Wreg[0][jl].z * q.z; a0.w += Wreg[0][jl].w * q.w;
                a1.x += Wreg[1][jl].x * q.x; a1.y += Wreg[1][jl].y * q.y;
                a1.z += Wreg[1][jl].z * q.z; a1.w += Wreg[1][jl].w * q.w;
                a2.x += Wreg[2][jl].x * q.x; a2.y += Wreg[2][jl].y * q.y;
                a2.z += Wreg[2][jl].z * q.z; a2.w += Wreg[2][jl].w * q.w;
                a3.x += Wreg[3][jl].x * q.x; a3.y += Wreg[3][jl].y * q.y;
                a3.z += Wreg[3][jl].z * q.z; a3.w += Wreg[3][jl].w * q.w;
            }
            float r0 = dpp_sum16((a0.x + a0.y) + (a0.z + a0.w));
            float r1 = dpp_sum16((a1.x + a1.y) + (a1.z + a1.w));
            float r2 = dpp_sum16((a2.x + a2.y) + (a2.z + a2.w));
            float r3 = dpp_sum16((a3.x + a3.y) + (a3.z + a3.w));
            if (kseg == 0) {
                int sg = slist[s0 + si];
                ((float4*)out)[(size_t)sg * 64 + ot * 16 + rg] =
                    make_float4(r0 + bias.x, r1 + bias.y, r2 + bias.z, r3 + bias.w);
            }
        }
    }
}

// ---- blocks 0..1023: in-place row L2-normalize ----
// ---- block 1024: finalize embed_norm (xsqp) and mask_norm (l1p, cnt8) ----
__global__ __launch_bounds__(256) void k_finish(float* __restrict__ out,
                                                const float* __restrict__ xsqp,
                                                const float* __restrict__ l1p,
                                                const int* __restrict__ cnt8) {
    int tid = threadIdx.x;
    if (blockIdx.x == 1024) {
        __shared__ float part[4];
        float s = 0.f;
        #pragma unroll
        for (int j = 0; j < 8; ++j) s += xsqp[tid * 8 + j];
        s = wave_reduce_sum(s);
        int wid = tid >> 6, lane = tid & 63;
        if (lane == 0) part[wid] = s;
        __syncthreads();
        if (tid < 64) {
            float l1 = (l1p[tid * 4 + 0] + l1p[tid * 4 + 1]) + (l1p[tid * 4 + 2] + l1p[tid * 4 + 3]);
            int cs = 0;
            #pragma unroll
            for (int j = 0; j < 8; ++j) cs += cnt8[tid * 8 + j];
            float mv = l1 * (float)cs;
            mv = wave_reduce_sum(mv);
            if (tid == 0) out[BD] = mv;                                               // mask_norm
        }
        if (tid == 0) out[BD + 1] = sqrtf((part[0] + part[1]) + (part[2] + part[3])); // embed_norm
        return;
    }
    int rowv = blockIdx.x * 4 + (tid >> 6);   // 4096 rows, wave per row
    int lane = tid & 63;
    float4* p = (float4*)out + (size_t)rowv * 64 + lane;
    float4 v = *p;
    float s = v.x * v.x + v.y * v.y + v.z * v.z + v.w * v.w;
    s = wave_reduce_sum(s);
    float inv = 1.0f / fmaxf(sqrtf(s), 1e-10f);
    v.x *= inv; v.y *= inv; v.z *= inv; v.w *= inv;
    *p = v;
}

extern "C" void kernel_launch(void* const* d_in, const int* in_sizes, int n_in,
                              void* d_out, int out_size, void* d_ws, size_t ws_size,
                              hipStream_t stream) {
    const float* x = (const float*)d_in[0];
    const float* W = (const float*)d_in[1];
    const float* b = (const float*)d_in[2];
    const int*   c = (const int*)d_in[3];
    float* out = (float*)d_out;

    float* xsqp = (float*)d_ws;           // 2048
    float* l1p  = xsqp + 2048;            // 256
    int*   cnt8 = (int*)(l1p + 256);      // 512

    k_main<<<2048, 256, 0, stream>>>(W, b, x, c, out, l1p, xsqp, cnt8);
    k_finish<<<1025, 256, 0, stream>>>(out, xsqp, l1p, cnt8);
}

// Round 10
// 20.960 us; speedup vs baseline: 1.4485x; 1.4485x over previous
//
#include <hip/hip_runtime.h>
#include <math.h>

#define B_ 4096
#define D_ 256
#define C_ 64
#define BD (B_*D_)

typedef __attribute__((ext_vector_type(8))) short bf16x8;
typedef __attribute__((ext_vector_type(4))) float f32x4;

__device__ __forceinline__ float wave_reduce_sum(float v) {
    #pragma unroll
    for (int off = 1; off < 64; off <<= 1) v += __shfl_xor(v, off);
    return v;
}

// sum across each aligned 16-lane group (VALU-only DPP row_ror)
__device__ __forceinline__ float dpp_sum16(float v) {
    int t;
    t = __builtin_amdgcn_update_dpp(0, __float_as_int(v), 0x121, 0xF, 0xF, true); v += __int_as_float(t);
    t = __builtin_amdgcn_update_dpp(0, __float_as_int(v), 0x122, 0xF, 0xF, true); v += __int_as_float(t);
    t = __builtin_amdgcn_update_dpp(0, __float_as_int(v), 0x124, 0xF, 0xF, true); v += __int_as_float(t);
    t = __builtin_amdgcn_update_dpp(0, __float_as_int(v), 0x128, 0xF, 0xF, true); v += __int_as_float(t);
    return v;
}

__device__ __forceinline__ unsigned cvtpk(float lo, float hi) {
    unsigned r;
    asm volatile("v_cvt_pk_bf16_f32 %0, %1, %2" : "=v"(r) : "v"(lo), "v"(hi));
    return r;
}

// convert one W row-slab (32 fp32 in wr[8]) to bf16 and store to LDS row (20 uints, 80B stride)
__device__ __forceinline__ void cvt_store(const float4* wr, unsigned* dst, int do_l1, float& l1acc) {
    #pragma unroll
    for (int q = 0; q < 4; ++q) {
        uint4 pk;
        pk.x = cvtpk(wr[2*q].x,   wr[2*q].y);
        pk.y = cvtpk(wr[2*q].z,   wr[2*q].w);
        pk.z = cvtpk(wr[2*q+1].x, wr[2*q+1].y);
        pk.w = cvtpk(wr[2*q+1].z, wr[2*q+1].w);
        *(uint4*)(dst + q*4) = pk;
    }
    if (do_l1) {
        #pragma unroll
        for (int j = 0; j < 8; ++j)
            l1acc += fabsf(wr[j].x) + fabsf(wr[j].y) + fabsf(wr[j].z) + fabsf(wr[j].w);
    }
}

// ---- fused MFMA kernel: grid = 64 conds x 4 sample-slices = 256 blocks ----
// Each block: full 256-col output for its slice's samples; in-block row normalize.
__global__ __launch_bounds__(256, 1) void k_main(const float* __restrict__ W,
                                                 const float* __restrict__ b,
                                                 const float* __restrict__ x,
                                                 const int* __restrict__ c,
                                                 float* __restrict__ out,
                                                 float* __restrict__ l1p,
                                                 float* __restrict__ xsqp,
                                                 int* __restrict__ cnt4) {
    int hw = blockIdx.x;
    int bid = (hw & 7) * 32 + (hw >> 3);    // XCD swizzle: cond's 4 blocks share an XCD
    int cond = bid >> 2;
    int sl = bid & 3;
    int tid = threadIdx.x;
    int wv = tid >> 6, lane = tid & 63;
    int g = lane >> 4, fr = lane & 15;

    // ---- early independent loads: x stripe, c slice, W slab0, bias ----
    const float4* x4 = (const float4*)x;
    float4 xv[4];
    #pragma unroll
    for (int t = 0; t < 4; ++t) xv[t] = x4[bid * 1024 + t * 256 + tid];
    int4 cvq[4];
    #pragma unroll
    for (int t = 0; t < 4; ++t) cvq[t] = ((const int4*)c)[t * 256 + tid];
    const float4* Wc4 = (const float4*)(W + (size_t)cond * 65536);
    float4 wrA[8], wrB[8];
    #pragma unroll
    for (int j = 0; j < 8; ++j) wrA[j] = Wc4[tid * 64 + j];          // slab 0 (row=tid, k 0..31)
    float bias_v[4];
    #pragma unroll
    for (int nt = 0; nt < 4; ++nt) bias_v[nt] = b[cond * 256 + wv * 64 + nt * 16 + fr];

    __shared__ unsigned Xl[64 * 128];        // 64 samples x 512B bf16 rows (XOR-swizzled)
    __shared__ unsigned Wl[2][256 * 20];     // dbuf W slab: 256 cols x 80B (32 k bf16 + pad)
    __shared__ float wsums[4][64];
    __shared__ float part_x[4];
    __shared__ float part_w[4];
    __shared__ int slist[64];
    __shared__ int nlist;
    if (tid == 0) nlist = 0;

    // ---- x copy to out tail + sumsq partial ----
    float2* dst = (float2*)(out + BD + 2);
    float s = 0.f;
    #pragma unroll
    for (int t = 0; t < 4; ++t) {
        int xi = bid * 1024 + t * 256 + tid;
        dst[2 * xi]     = make_float2(xv[t].x, xv[t].y);
        dst[2 * xi + 1] = make_float2(xv[t].z, xv[t].w);
        s += xv[t].x * xv[t].x + xv[t].y * xv[t].y + xv[t].z * xv[t].z + xv[t].w * xv[t].w;
    }
    s = wave_reduce_sum(s);
    if (lane == 0) part_x[wv] = s;
    __syncthreads();

    // ---- slice scan: slice sl owns samples i == sl (mod 4) ----
    #pragma unroll
    for (int t = 0; t < 4; ++t) {
        int4 q = cvq[t];
        int cc = (sl == 0) ? q.x : (sl == 1) ? q.y : (sl == 2) ? q.z : q.w;
        if (cc == cond) {
            int p = atomicAdd(&nlist, 1);
            if (p < 64) slist[p] = 4 * (t * 256 + tid) + sl;
        }
    }
    __syncthreads();
    int n = min(nlist, 64);
    int mts = (n + 15) >> 4;
    if (tid == 0) {
        xsqp[bid] = (part_x[0] + part_x[1]) + (part_x[2] + part_x[3]);
        cnt4[bid] = n;
    }

    // ---- stage X: gather fp32 rows -> bf16 LDS, XOR swizzle ((row&7)<<4) ----
    for (int u = tid; u < n * 64; u += 256) {
        int si = u >> 6, v = u & 63;
        int sg = slist[si];
        float4 q = x4[(size_t)sg * 64 + v];
        int off = (v * 8) ^ ((si & 7) << 4);
        Xl[si * 128 + (off >> 2)]     = cvtpk(q.x, q.y);
        Xl[si * 128 + (off >> 2) + 1] = cvtpk(q.z, q.w);
    }

    float l1acc = 0.f;
    cvt_store(wrA, &Wl[0][tid * 20], sl == 0, l1acc);   // slab 0 -> buf 0
    #pragma unroll
    for (int j = 0; j < 8; ++j) wrB[j] = Wc4[tid * 64 + 8 + j];      // slab 1
    __syncthreads();

    // ---- K loop: 8 slabs, dbuf, fully unrolled ----
    f32x4 acc[4][4];
    #pragma unroll
    for (int mt = 0; mt < 4; ++mt)
        #pragma unroll
        for (int nt = 0; nt < 4; ++nt)
            acc[mt][nt] = (f32x4){0.f, 0.f, 0.f, 0.f};

    #pragma unroll
    for (int kk = 0; kk < 8; ++kk) {
        const unsigned* Wb = Wl[kk & 1];
        bf16x8 bfr[4];
        #pragma unroll
        for (int nt = 0; nt < 4; ++nt)
            bfr[nt] = *(const bf16x8*)((const char*)Wb + ((wv * 64 + nt * 16 + fr) * 20 + g * 4) * 4);
        #pragma unroll
        for (int mt = 0; mt < 4; ++mt) if (mt < mts) {
            int row = mt * 16 + fr;
            bf16x8 afr = *(const bf16x8*)((const char*)Xl + row * 512 + ((kk * 64 + g * 16) ^ ((row & 7) << 4)));
            #pragma unroll
            for (int nt = 0; nt < 4; ++nt)
                acc[mt][nt] = __builtin_amdgcn_mfma_f32_16x16x32_bf16(afr, bfr[nt], acc[mt][nt], 0, 0, 0);
        }
        if (kk < 7) {
            if ((kk & 1) == 0) {
                cvt_store(wrB, &Wl[1][tid * 20], sl == 0, l1acc);
                if (kk < 6) {
                    #pragma unroll
                    for (int j = 0; j < 8; ++j) wrA[j] = Wc4[tid * 64 + (kk + 2) * 8 + j];
                }
            } else {
                cvt_store(wrA, &Wl[0][tid * 20], sl == 0, l1acc);
                if (kk < 6) {
                    #pragma unroll
                    for (int j = 0; j < 8; ++j) wrB[j] = Wc4[tid * 64 + (kk + 2) * 8 + j];
                }
            }
            __syncthreads();
        }
    }

    // ---- bias add + per-wave row sums ----
    #pragma unroll
    for (int mt = 0; mt < 4; ++mt) if (mt < mts) {
        #pragma unroll
        for (int nt = 0; nt < 4; ++nt)
            #pragma unroll
            for (int j = 0; j < 4; ++j)
                acc[mt][nt][j] += bias_v[nt];
    }
    if (sl == 0) {
        float a = wave_reduce_sum(l1acc);
        if (lane == 0) part_w[wv] = a;
    }
    #pragma unroll
    for (int mt = 0; mt < 4; ++mt) if (mt < mts) {
        #pragma unroll
        for (int j = 0; j < 4; ++j) {
            float sj = acc[mt][0][j] * acc[mt][0][j] + acc[mt][1][j] * acc[mt][1][j]
                     + acc[mt][2][j] * acc[mt][2][j] + acc[mt][3][j] * acc[mt][3][j];
            sj = dpp_sum16(sj);
            if (fr == 0) wsums[wv][mt * 16 + g * 4 + j] = sj;
        }
    }
    __syncthreads();
    if (sl == 0 && tid == 0)
        l1p[cond] = (part_w[0] + part_w[1]) + (part_w[2] + part_w[3]);

    // ---- normalize + store ----
    #pragma unroll
    for (int mt = 0; mt < 4; ++mt) if (mt < mts) {
        #pragma unroll
        for (int j = 0; j < 4; ++j) {
            int row = mt * 16 + g * 4 + j;
            if (row < n) {
                float tot = wsums[0][row] + wsums[1][row] + wsums[2][row] + wsums[3][row];
                float inv = 1.0f / fmaxf(sqrtf(tot), 1e-10f);
                int sgl = slist[row];
                float* op = out + (size_t)sgl * 256 + wv * 64 + fr;
                #pragma unroll
                for (int nt = 0; nt < 4; ++nt)
                    op[nt * 16] = acc[mt][nt][j] * inv;
            }
        }
    }
}

// ---- 1 block: finalize embed_norm and mask_norm ----
__global__ __launch_bounds__(256) void k_fin(const float* __restrict__ xsqp,
                                             const float* __restrict__ l1p,
                                             const int* __restrict__ cnt4,
                                             float* __restrict__ out) {
    int tid = threadIdx.x;
    int wv = tid >> 6, lane = tid & 63;
    __shared__ float part[4];
    float s = xsqp[tid];
    s = wave_reduce_sum(s);
    if (lane == 0) part[wv] = s;
    __syncthreads();
    if (tid == 0) out[BD + 1] = sqrtf((part[0] + part[1]) + (part[2] + part[3]));
    if (tid < 64) {
        float mv = l1p[tid] * (float)(cnt4[4 * tid] + cnt4[4 * tid + 1] + cnt4[4 * tid + 2] + cnt4[4 * tid + 3]);
        mv = wave_reduce_sum(mv);
        if (tid == 0) out[BD] = mv;
    }
}

extern "C" void kernel_launch(void* const* d_in, const int* in_sizes, int n_in,
                              void* d_out, int out_size, void* d_ws, size_t ws_size,
                              hipStream_t stream) {
    const float* x = (const float*)d_in[0];
    const float* W = (const float*)d_in[1];
    const float* b = (const float*)d_in[2];
    const int*   c = (const int*)d_in[3];
    float* out = (float*)d_out;

    float* xsqp = (float*)d_ws;           // 256
    float* l1p  = xsqp + 256;             // 64
    int*   cnt4 = (int*)(l1p + 64);       // 256

    k_main<<<256, 256, 0, stream>>>(W, b, x, c, out, l1p, xsqp, cnt4);
    k_fin<<<1, 256, 0, stream>>>(xsqp, l1p, cnt4, out);
}